// Round 7
// baseline (111.161 us; speedup 1.0000x reference)
//
#include <hip/hip_runtime.h>

#define INPUT_SIZE 128
#define OUTPUT_SIZE 128
#define HIDDEN 8
#define BATCH 1024

#define ICH 16                   // i-chunks (blockIdx.y)
#define IPC (INPUT_SIZE / ICH)   // 8 i's per chunk
#define TPB 128                  // threads per block (2 waves)
#define BPT 8                    // batch elements per thread -> 128*8 = 1024

typedef __fp16 half2v __attribute__((ext_vector_type(2)));

#if defined(__has_builtin)
#if __has_builtin(__builtin_amdgcn_fdot2)
#define HAS_FDOT2 1
#endif
#endif
#ifndef HAS_FDOT2
#define HAS_FDOT2 0
#endif

// ---------------------------------------------------------------------------
// Prep (merged): blocks 0..127 transpose x [B,I]->xT [I,B];
// blocks 128..1151 convert W2 fp32 -> f16 (pkrtz) into ws.
// 256 threads/block.
// ---------------------------------------------------------------------------
__global__ void prep_kernel(const float* __restrict__ x,
                            const float* __restrict__ W2,
                            float* __restrict__ xT,
                            __fp16* __restrict__ W2h) {
    if (blockIdx.x < 128) {
        __shared__ float tile[32][33];
        const int bx = blockIdx.x;
        const int i0 = (bx & 3) * 32;
        const int b0 = (bx >> 2) * 32;
        const int tx = threadIdx.x & 31;
        const int ty = threadIdx.x >> 5;   // 0..7
#pragma unroll
        for (int r = ty; r < 32; r += 8)
            tile[r][tx] = x[(b0 + r) * INPUT_SIZE + (i0 + tx)];
        __syncthreads();
#pragma unroll
        for (int r = ty; r < 32; r += 8)
            xT[(i0 + r) * BATCH + (b0 + tx)] = tile[tx][r];
    } else {
        // 1024 blocks x 256 threads x 4 floats = 1,048,576 = 16384*64
        const size_t idx = (size_t)(blockIdx.x - 128) * 256 + threadIdx.x;
        const float4 v = *(const float4*)(W2 + 4 * idx);
        const half2v a = __builtin_amdgcn_cvt_pkrtz(v.x, v.y);
        const half2v b = __builtin_amdgcn_cvt_pkrtz(v.z, v.w);
        float2 st;
        st.x = __builtin_bit_cast(float, a);
        st.y = __builtin_bit_cast(float, b);
        *(float2*)(W2h + 4 * idx) = st;
    }
}

__global__ void zero_out_kernel(float* __restrict__ out, int n) {
    int idx = blockIdx.x * blockDim.x + threadIdx.x;
    if (idx < n) out[idx] = 0.0f;
}

// ---------------------------------------------------------------------------
// Main kernel, LDS-free. block=(o,ic); per i: weights loaded directly
// global->VGPR (lane-uniform -> L1 broadcast), W2 as f16 (32 VGPRs).
// Layer 2 via v_dot2_f32_f16 (2 FMA/inst, f32 accum). No barriers; latency
// hidden by waves. ~69 VALU inst per (i,j) vs 97+ fp32.
// ---------------------------------------------------------------------------
template <bool PARTIALS>
__global__ __launch_bounds__(TPB, 3)
void mlpkan_kernel(const float* __restrict__ xT,
                   const float* __restrict__ W1, const float* __restrict__ b1,
                   const __fp16* __restrict__ W2h, const float* __restrict__ b2,
                   const float* __restrict__ W3, const float* __restrict__ b3,
                   float* __restrict__ partials, float* __restrict__ out) {
    const int o   = blockIdx.x;
    const int ic  = blockIdx.y;
    const int tid = threadIdx.x;

    float acc[BPT];
#pragma unroll
    for (int j = 0; j < BPT; ++j) acc[j] = 0.0f;

#pragma unroll 1
    for (int ii = 0; ii < IPC; ++ii) {
        const int i = ic * IPC + ii;
        const int n = i * OUTPUT_SIZE + o;          // block-uniform

        // x values (coalesced dword loads)
        float s[BPT];
#pragma unroll
        for (int j = 0; j < BPT; ++j)
            s[j] = xT[(size_t)i * BATCH + tid + j * TPB];

        // ---- weights: direct global->reg, lane-uniform addresses ----
        const float4 w1a = *(const float4*)(W1 + (size_t)n * 8);
        const float4 w1b = *(const float4*)(W1 + (size_t)n * 8 + 4);
        const float4 b1a = *(const float4*)(b1 + (size_t)n * 8);
        const float4 b1b = *(const float4*)(b1 + (size_t)n * 8 + 4);
        const float4 b2a = *(const float4*)(b2 + (size_t)n * 8);
        const float4 b2b = *(const float4*)(b2 + (size_t)n * 8 + 4);
        const float4 w3a = *(const float4*)(W3 + (size_t)n * 8);
        const float4 w3b = *(const float4*)(W3 + (size_t)n * 8 + 4);
        const float  bb3 = b3[n];

        // W2 row h (8 f16 = 16B) as 4 half2 pairs along k
        half2v w2p[8][4];
#pragma unroll
        for (int h = 0; h < 8; ++h) {
            const float4 row = *(const float4*)((const char*)W2h + (size_t)n * 128 + h * 16);
            w2p[h][0] = __builtin_bit_cast(half2v, row.x);
            w2p[h][1] = __builtin_bit_cast(half2v, row.y);
            w2p[h][2] = __builtin_bit_cast(half2v, row.z);
            w2p[h][3] = __builtin_bit_cast(half2v, row.w);
        }

        const float w1r[8] = {w1a.x, w1a.y, w1a.z, w1a.w, w1b.x, w1b.y, w1b.z, w1b.w};
        const float b1r[8] = {b1a.x, b1a.y, b1a.z, b1a.w, b1b.x, b1b.y, b1b.z, b1b.w};
        const float b2r[8] = {b2a.x, b2a.y, b2a.z, b2a.w, b2b.x, b2b.y, b2b.z, b2b.w};
        const float w3r[8] = {w3a.x, w3a.y, w3a.z, w3a.w, w3b.x, w3b.y, w3b.z, w3b.w};

#pragma unroll
        for (int j = 0; j < BPT; ++j) {
            const float sj = s[j];
            float h1[8];
#pragma unroll
            for (int k = 0; k < 8; ++k)
                h1[k] = fmaxf(fmaf(w1r[k], sj, b1r[k]), 0.0f);

#if HAS_FDOT2
            half2v hp[4];
#pragma unroll
            for (int q = 0; q < 4; ++q)
                hp[q] = __builtin_amdgcn_cvt_pkrtz(h1[2 * q], h1[2 * q + 1]);

            float h2[8];
#pragma unroll
            for (int h = 0; h < 8; ++h) {
                float v = b2r[h];
#pragma unroll
                for (int q = 0; q < 4; ++q)
                    v = __builtin_amdgcn_fdot2(w2p[h][q], hp[q], v, false);
                h2[h] = fmaxf(v, 0.0f);
            }
#else
            float h2[8];
#pragma unroll
            for (int h = 0; h < 8; ++h) {
                float v = b2r[h];
#pragma unroll
                for (int q = 0; q < 4; ++q) {
                    v = fmaf((float)w2p[h][q][0], h1[2 * q], v);
                    v = fmaf((float)w2p[h][q][1], h1[2 * q + 1], v);
                }
                h2[h] = fmaxf(v, 0.0f);
            }
#endif
            float v3 = bb3;
#pragma unroll
            for (int k = 0; k < 8; ++k)
                v3 = fmaf(w3r[k], h2[k], v3);
            acc[j] += v3;
        }
    }

    if (PARTIALS) {
#pragma unroll
        for (int j = 0; j < BPT; ++j)
            partials[((size_t)ic * OUTPUT_SIZE + o) * BATCH + tid + j * TPB] = acc[j];
    } else {
#pragma unroll
        for (int j = 0; j < BPT; ++j)
            atomicAdd(&out[(size_t)(tid + j * TPB) * OUTPUT_SIZE + o], acc[j]);
    }
}

// ---------------------------------------------------------------------------
// Reduce ICH partials [ic][o][b] -> out [b][o] with LDS transpose.
// grid: (OUTPUT/32, BATCH/32), block: (32,16)
// ---------------------------------------------------------------------------
__global__ void reduce_kernel(const float* __restrict__ partials,
                              float* __restrict__ out) {
    __shared__ float tile[32][33];
    const int o0 = blockIdx.x * 32;
    const int b0 = blockIdx.y * 32;
    const int tx = threadIdx.x;
    const int ty = threadIdx.y;
#pragma unroll
    for (int r = ty; r < 32; r += 16) {
        float v = 0.0f;
#pragma unroll
        for (int icc = 0; icc < ICH; ++icc)
            v += partials[((size_t)icc * OUTPUT_SIZE + o0 + r) * BATCH + b0 + tx];
        tile[r][tx] = v;
    }
    __syncthreads();
#pragma unroll
    for (int r = ty; r < 32; r += 16)
        out[(size_t)(b0 + r) * OUTPUT_SIZE + o0 + tx] = tile[tx][r];
}

extern "C" void kernel_launch(void* const* d_in, const int* in_sizes, int n_in,
                              void* d_out, int out_size, void* d_ws, size_t ws_size,
                              hipStream_t stream) {
    const float* x  = (const float*)d_in[0];
    const float* W1 = (const float*)d_in[1];
    const float* b1 = (const float*)d_in[2];
    const float* W2 = (const float*)d_in[3];
    const float* b2 = (const float*)d_in[4];
    const float* W3 = (const float*)d_in[5];
    const float* b3 = (const float*)d_in[6];
    float* out = (float*)d_out;

    const size_t xt_elems   = (size_t)INPUT_SIZE * BATCH;               // 128K
    const size_t part_elems = (size_t)ICH * OUTPUT_SIZE * BATCH;        // 2M
    const size_t w2h_bytes  = (size_t)16384 * 64 * sizeof(__fp16);      // 2MB
    const size_t need_bytes = (xt_elems + part_elems) * sizeof(float) + w2h_bytes;

    dim3 mgrid(OUTPUT_SIZE, ICH);

    if (ws_size >= need_bytes) {
        float*   xT       = (float*)d_ws;
        float*   partials = xT + xt_elems;
        __fp16*  W2h      = (__fp16*)(partials + part_elems);

        prep_kernel<<<1152, 256, 0, stream>>>(x, W2, xT, W2h);
        mlpkan_kernel<true><<<mgrid, TPB, 0, stream>>>(xT, W1, b1, W2h, b2, W3, b3,
                                                       partials, out);
        dim3 rgrid(OUTPUT_SIZE / 32, BATCH / 32);
        reduce_kernel<<<rgrid, dim3(32, 16), 0, stream>>>(partials, out);
    } else {
        const int nz = BATCH * OUTPUT_SIZE;
        zero_out_kernel<<<(nz + 255) / 256, 256, 0, stream>>>(out, nz);
        if (ws_size >= xt_elems * sizeof(float) + w2h_bytes) {
            float*  xT  = (float*)d_ws;
            __fp16* W2h = (__fp16*)(xT + xt_elems);
            prep_kernel<<<1152, 256, 0, stream>>>(x, W2, xT, W2h);
            mlpkan_kernel<false><<<mgrid, TPB, 0, stream>>>(xT, W1, b1, W2h, b2, W3, b3,
                                                            nullptr, out);
        }
    }
}

// Round 8
// 110.685 us; speedup vs baseline: 1.0043x; 1.0043x over previous
//
#include <hip/hip_runtime.h>

#define INPUT_SIZE 128
#define OUTPUT_SIZE 128
#define HIDDEN 8
#define BATCH 1024

#define ICH 16                   // i-chunks (blockIdx.y)
#define IPC (INPUT_SIZE / ICH)   // 8 i's per chunk
#define TPB 128                  // threads per block (2 waves)
#define BPT 8                    // batch elements per thread
#define SLOT 68                  // dwords per i-slot in LDS (65 used + pad)

typedef __fp16 half2v __attribute__((ext_vector_type(2)));

#if defined(__has_builtin)
#if __has_builtin(__builtin_amdgcn_fdot2)
#define HAS_FDOT2 1
#endif
#endif
#ifndef HAS_FDOT2
#define HAS_FDOT2 0
#endif

// ---------------------------------------------------------------------------
// Prep: blocks 0..127 transpose x [B,I]->xT [I,B]; blocks 128..1151 convert
// W2 fp32 -> f16 into ws.
// ---------------------------------------------------------------------------
__global__ void prep_kernel(const float* __restrict__ x,
                            const float* __restrict__ W2,
                            float* __restrict__ xT,
                            __fp16* __restrict__ W2h) {
    if (blockIdx.x < 128) {
        __shared__ float tile[32][33];
        const int bx = blockIdx.x;
        const int i0 = (bx & 3) * 32;
        const int b0 = (bx >> 2) * 32;
        const int tx = threadIdx.x & 31;
        const int ty = threadIdx.x >> 5;
#pragma unroll
        for (int r = ty; r < 32; r += 8)
            tile[r][tx] = x[(b0 + r) * INPUT_SIZE + (i0 + tx)];
        __syncthreads();
#pragma unroll
        for (int r = ty; r < 32; r += 8)
            xT[(i0 + r) * BATCH + (b0 + tx)] = tile[tx][r];
    } else {
        const size_t idx = (size_t)(blockIdx.x - 128) * 256 + threadIdx.x;
        const float4 v = *(const float4*)(W2 + 4 * idx);
        const half2v a = __builtin_amdgcn_cvt_pkrtz(v.x, v.y);
        const half2v b = __builtin_amdgcn_cvt_pkrtz(v.z, v.w);
        float2 st;
        st.x = __builtin_bit_cast(float, a);
        st.y = __builtin_bit_cast(float, b);
        *(float2*)(W2h + 4 * idx) = st;
    }
}

__global__ void zero_out_kernel(float* __restrict__ out, int n) {
    int idx = blockIdx.x * blockDim.x + threadIdx.x;
    if (idx < n) out[idx] = 0.0f;
}

// ---------------------------------------------------------------------------
// Main kernel. block=(o,ic). Stage IPC slots of weights in LDS once
// (slot: w1@0 b1@8 b2@16 w3@24 b3@32 W2h@36..67, stride 68 dwords).
// Per i, two REGISTER-LIGHT phases:
//   phase1 (w1,b1 = 16 regs): h1 for all 8 j -> packed f16 h1p[8][4] (32 regs)
//   phase2 (W2h,b2,w3,b3 = 33 regs): fdot2 dots + relu + L3 + acc
// Batches: thread t owns b = 4t..4t+3 and 512+4t..512+4t+3 (float4 x loads).
// ---------------------------------------------------------------------------
template <bool PARTIALS>
__global__ __launch_bounds__(TPB, 4)
void mlpkan_kernel(const float* __restrict__ xT,
                   const float* __restrict__ W1, const float* __restrict__ b1,
                   const __fp16* __restrict__ W2h, const float* __restrict__ b2,
                   const float* __restrict__ W3, const float* __restrict__ b3,
                   float* __restrict__ partials, float* __restrict__ out) {
    __shared__ float wlds[IPC * SLOT];

    const int o   = blockIdx.x;
    const int ic  = blockIdx.y;
    const int tid = threadIdx.x;

    // ---- stage this block's weights into LDS (16 threads per i-slot) ----
    {
        const int ii  = tid >> 4;
        const int idx = tid & 15;
        const int n   = (ic * IPC + ii) * OUTPUT_SIZE + o;
        float4 v;
        int dst;
        if (idx < 2) {
            v = *(const float4*)(W1 + (size_t)n * 8 + idx * 4);          dst = 0  + idx * 4;
        } else if (idx < 4) {
            v = *(const float4*)(b1 + (size_t)n * 8 + (idx - 2) * 4);    dst = 8  + (idx - 2) * 4;
        } else if (idx < 6) {
            v = *(const float4*)(b2 + (size_t)n * 8 + (idx - 4) * 4);    dst = 16 + (idx - 4) * 4;
        } else if (idx < 8) {
            v = *(const float4*)(W3 + (size_t)n * 8 + (idx - 6) * 4);    dst = 24 + (idx - 6) * 4;
        } else {
            v = *(const float4*)((const char*)W2h + (size_t)n * 128 + (idx - 8) * 16);
            dst = 36 + (idx - 8) * 4;
        }
        *(float4*)&wlds[ii * SLOT + dst] = v;
        if (idx == 0) wlds[ii * SLOT + 32] = b3[n];
    }
    __syncthreads();

    float acc[BPT];
#pragma unroll
    for (int j = 0; j < BPT; ++j) acc[j] = 0.0f;

#pragma unroll 1
    for (int ii = 0; ii < IPC; ++ii) {
        const int i = ic * IPC + ii;
        const float* w = &wlds[ii * SLOT];

        // x: two coalesced float4 loads (b = 4t.. and 512+4t..)
        const float4 sA = *(const float4*)(xT + (size_t)i * BATCH + 4 * tid);
        const float4 sB = *(const float4*)(xT + (size_t)i * BATCH + 512 + 4 * tid);
        const float s[BPT] = {sA.x, sA.y, sA.z, sA.w, sB.x, sB.y, sB.z, sB.w};

        // ---------------- phase 1: layer 1 for all j ----------------
        const float4 w1a = *(const float4*)(w + 0);
        const float4 w1b = *(const float4*)(w + 4);
        const float4 b1a = *(const float4*)(w + 8);
        const float4 b1b = *(const float4*)(w + 12);
        const float w1r[8] = {w1a.x, w1a.y, w1a.z, w1a.w, w1b.x, w1b.y, w1b.z, w1b.w};
        const float b1r[8] = {b1a.x, b1a.y, b1a.z, b1a.w, b1b.x, b1b.y, b1b.z, b1b.w};

        half2v h1p[BPT][4];
#pragma unroll
        for (int j = 0; j < BPT; ++j) {
            const float sj = s[j];
            float h1[8];
#pragma unroll
            for (int k = 0; k < 8; ++k)
                h1[k] = fmaxf(fmaf(w1r[k], sj, b1r[k]), 0.0f);
#pragma unroll
            for (int q = 0; q < 4; ++q)
                h1p[j][q] = __builtin_amdgcn_cvt_pkrtz(h1[2 * q], h1[2 * q + 1]);
        }

        // ---------------- phase 2: layers 2+3 for all j ----------------
        const float4 b2a = *(const float4*)(w + 16);
        const float4 b2b = *(const float4*)(w + 20);
        const float4 w3a = *(const float4*)(w + 24);
        const float4 w3b = *(const float4*)(w + 28);
        const float  b3r = w[32];
        const float b2r[8] = {b2a.x, b2a.y, b2a.z, b2a.w, b2b.x, b2b.y, b2b.z, b2b.w};
        const float w3r[8] = {w3a.x, w3a.y, w3a.z, w3a.w, w3b.x, w3b.y, w3b.z, w3b.w};

        half2v w2p[8][4];
#pragma unroll
        for (int r = 0; r < 8; ++r) {
            const float4 row = *(const float4*)(w + 36 + 4 * r);   // row h=r: 4 half2
            w2p[r][0] = __builtin_bit_cast(half2v, row.x);
            w2p[r][1] = __builtin_bit_cast(half2v, row.y);
            w2p[r][2] = __builtin_bit_cast(half2v, row.z);
            w2p[r][3] = __builtin_bit_cast(half2v, row.w);
        }

#pragma unroll
        for (int j = 0; j < BPT; ++j) {
            float h2[8];
#if HAS_FDOT2
#pragma unroll
            for (int h = 0; h < 8; ++h) {
                float v = b2r[h];
#pragma unroll
                for (int q = 0; q < 4; ++q)
                    v = __builtin_amdgcn_fdot2(w2p[h][q], h1p[j][q], v, false);
                h2[h] = fmaxf(v, 0.0f);
            }
#else
#pragma unroll
            for (int h = 0; h < 8; ++h) {
                float v = b2r[h];
#pragma unroll
                for (int q = 0; q < 4; ++q) {
                    v = fmaf((float)w2p[h][q][0], (float)h1p[j][q][0], v);
                    v = fmaf((float)w2p[h][q][1], (float)h1p[j][q][1], v);
                }
                h2[h] = fmaxf(v, 0.0f);
            }
#endif
            float v3 = b3r;
#pragma unroll
            for (int k = 0; k < 8; ++k)
                v3 = fmaf(w3r[k], h2[k], v3);
            acc[j] += v3;
        }
    }

    if (PARTIALS) {
        float* base = partials + ((size_t)ic * OUTPUT_SIZE + o) * BATCH;
        float4 pa = {acc[0], acc[1], acc[2], acc[3]};
        float4 pb = {acc[4], acc[5], acc[6], acc[7]};
        *(float4*)(base + 4 * tid)       = pa;
        *(float4*)(base + 512 + 4 * tid) = pb;
    } else {
#pragma unroll
        for (int j = 0; j < BPT; ++j) {
            const int b = (j < 4) ? (4 * tid + j) : (512 + 4 * tid + (j - 4));
            atomicAdd(&out[(size_t)b * OUTPUT_SIZE + o], acc[j]);
        }
    }
}

// ---------------------------------------------------------------------------
// Reduce ICH partials [ic][o][b] -> out [b][o] with LDS transpose.
// grid: (OUTPUT/32, BATCH/32), block: (32,16)
// ---------------------------------------------------------------------------
__global__ void reduce_kernel(const float* __restrict__ partials,
                              float* __restrict__ out) {
    __shared__ float tile[32][33];
    const int o0 = blockIdx.x * 32;
    const int b0 = blockIdx.y * 32;
    const int tx = threadIdx.x;
    const int ty = threadIdx.y;
#pragma unroll
    for (int r = ty; r < 32; r += 16) {
        float v = 0.0f;
#pragma unroll
        for (int icc = 0; icc < ICH; ++icc)
            v += partials[((size_t)icc * OUTPUT_SIZE + o0 + r) * BATCH + b0 + tx];
        tile[r][tx] = v;
    }
    __syncthreads();
#pragma unroll
    for (int r = ty; r < 32; r += 16)
        out[(size_t)(b0 + r) * OUTPUT_SIZE + o0 + tx] = tile[tx][r];
}

extern "C" void kernel_launch(void* const* d_in, const int* in_sizes, int n_in,
                              void* d_out, int out_size, void* d_ws, size_t ws_size,
                              hipStream_t stream) {
    const float* x  = (const float*)d_in[0];
    const float* W1 = (const float*)d_in[1];
    const float* b1 = (const float*)d_in[2];
    const float* W2 = (const float*)d_in[3];
    const float* b2 = (const float*)d_in[4];
    const float* W3 = (const float*)d_in[5];
    const float* b3 = (const float*)d_in[6];
    float* out = (float*)d_out;

    const size_t xt_elems   = (size_t)INPUT_SIZE * BATCH;               // 128K
    const size_t part_elems = (size_t)ICH * OUTPUT_SIZE * BATCH;        // 2M
    const size_t w2h_bytes  = (size_t)16384 * 64 * sizeof(__fp16);      // 2MB
    const size_t need_bytes = (xt_elems + part_elems) * sizeof(float) + w2h_bytes;

    dim3 mgrid(OUTPUT_SIZE, ICH);

    if (ws_size >= need_bytes) {
        float*   xT       = (float*)d_ws;
        float*   partials = xT + xt_elems;
        __fp16*  W2h      = (__fp16*)(partials + part_elems);

        prep_kernel<<<1152, 256, 0, stream>>>(x, W2, xT, W2h);
        mlpkan_kernel<true><<<mgrid, TPB, 0, stream>>>(xT, W1, b1, W2h, b2, W3, b3,
                                                       partials, out);
        dim3 rgrid(OUTPUT_SIZE / 32, BATCH / 32);
        reduce_kernel<<<rgrid, dim3(32, 16), 0, stream>>>(partials, out);
    } else {
        const int nz = BATCH * OUTPUT_SIZE;
        zero_out_kernel<<<(nz + 255) / 256, 256, 0, stream>>>(out, nz);
        if (ws_size >= xt_elems * sizeof(float) + w2h_bytes) {
            float*  xT  = (float*)d_ws;
            __fp16* W2h = (__fp16*)(xT + xt_elems);
            prep_kernel<<<1152, 256, 0, stream>>>(x, W2, xT, W2h);
            mlpkan_kernel<false><<<mgrid, TPB, 0, stream>>>(xT, W1, b1, W2h, b2, W3, b3,
                                                            nullptr, out);
        }
    }
}